// Round 6
// baseline (419.726 us; speedup 1.0000x reference)
//
#include <hip/hip_runtime.h>

#define D 128   // feature dim
#define H 64    // hidden dim of classifier

// ---------- bf16 helpers (bit-level, RNE) ----------

__device__ __forceinline__ unsigned int bf16_rne(float f) {
    unsigned int u = __float_as_uint(f);
    u += 0x7fffu + ((u >> 16) & 1u);
    return u >> 16;
}
__device__ __forceinline__ unsigned int pack_bf16(float a, float b) {
    return bf16_rne(a) | (bf16_rne(b) << 16);
}
__device__ __forceinline__ float bf16_lo(unsigned int u) { return __uint_as_float(u << 16); }
__device__ __forceinline__ float bf16_hi(unsigned int u) { return __uint_as_float(u & 0xffff0000u); }

// ---------- CSR construction ----------
// pass1: one atomic per edge gives within-node rank AND final counts.
// pass2 is fused into the gemm1 dispatch (independent work, opposite bottlenecks).

static __global__ void pass1_k(const int* __restrict__ ei, int E,
                               int* __restrict__ cnt, int* __restrict__ rank) {
    int e = blockIdx.x * blockDim.x + threadIdx.x;
    if (e < E) rank[e] = atomicAdd(&cnt[ei[E + e]], 1);
}

// scanA + dinv fused: block sums of cnt, and dinv = rsqrt(cnt+1) as by-product
static __global__ void scanA_k(const int* __restrict__ cnt, int n,
                               int* __restrict__ bsum, float* __restrict__ dinv) {
    __shared__ int s[256];
    int i = blockIdx.x * 256 + threadIdx.x;
    int v = (i < n) ? cnt[i] : 0;
    if (i < n) dinv[i] = rsqrtf((float)v + 1.0f);   // +1 self loop; deg >= 1 always
    s[threadIdx.x] = v;
    __syncthreads();
    for (int off = 128; off > 0; off >>= 1) {
        if ((int)threadIdx.x < off) s[threadIdx.x] += s[threadIdx.x + off];
        __syncthreads();
    }
    if (threadIdx.x == 0) bsum[blockIdx.x] = s[0];
}

// parallel exclusive scan of block sums, one 256-thread block
static __global__ __launch_bounds__(256) void scanB_k(int* __restrict__ bsum, int nb) {
    __shared__ int s[256];
    __shared__ int carry;
    if (threadIdx.x == 0) carry = 0;
    __syncthreads();
    for (int base = 0; base < nb; base += 256) {
        int i = base + threadIdx.x;
        int v = (i < nb) ? bsum[i] : 0;
        s[threadIdx.x] = v;
        __syncthreads();
        for (int off = 1; off < 256; off <<= 1) {
            int t = ((int)threadIdx.x >= off) ? s[threadIdx.x - off] : 0;
            __syncthreads();
            s[threadIdx.x] += t;
            __syncthreads();
        }
        if (i < nb) bsum[i] = carry + s[threadIdx.x] - v;   // exclusive
        __syncthreads();
        if (threadIdx.x == 255) carry += s[255];
        __syncthreads();
    }
}

static __global__ void scanC_k(const int* __restrict__ cnt, int n, const int* __restrict__ bsum,
                               int* __restrict__ rowptr) {
    __shared__ int s[256];
    int i = blockIdx.x * 256 + threadIdx.x;
    int v = (i < n) ? cnt[i] : 0;
    s[threadIdx.x] = v;
    __syncthreads();
    for (int off = 1; off < 256; off <<= 1) {
        int t = ((int)threadIdx.x >= off) ? s[threadIdx.x - off] : 0;
        __syncthreads();
        s[threadIdx.x] += t;
        __syncthreads();
    }
    if (i < n) {
        int excl = bsum[blockIdx.x] + s[threadIdx.x] - v;
        rowptr[i] = excl;
        if (i == n - 1) rowptr[n] = excl + v;
    }
}

// ---------- FAT: gemm layer-1 (fp32 x @ W1, pre-scaled bf16 out) ∥ CSR pass2 scatter ----------
// blocks [0, gb): 64-row gemm tile (r5 structure). blocks [gb, ...): pass2 scatter.
// Independent work; gemm is VALU-bound, pass2 is scatter-latency-bound -> co-schedule.

static __global__ __launch_bounds__(256) void gemm1_pass2_k(
        const float* __restrict__ x, const float* __restrict__ W,
        const float* __restrict__ dinv, unsigned int* __restrict__ hb, int n, int gb,
        const int* __restrict__ ei, int E, const int* __restrict__ rank,
        const int* __restrict__ rowptr, int* __restrict__ csr_src) {
    __shared__ float Ws[32 * D];     // [kk][col] 16 KB
    __shared__ float xT[32 * 64];    // [kk][row]  8 KB
    const int tid = threadIdx.x;
    if ((int)blockIdx.x >= gb) {     // ---- pass2: no-atomic scatter ----
        int e = ((int)blockIdx.x - gb) * 256 + tid;
        if (e < E) {
            int d = ei[E + e];
            csr_src[rowptr[d] + rank[e]] = ei[e];
        }
        return;
    }
    // ---- gemm1 ----
    const int row0 = blockIdx.x * 64;
    const int tx = tid & 31;        // cols 4*tx .. 4*tx+3
    const int ty = tid >> 5;        // rows 8*ty .. 8*ty+7
    const int sr = tid & 63;        // staging row
    const int sk = (tid >> 6) * 4;  // staging k-offset
    const int gr = row0 + sr;

    float acc[8][4];
#pragma unroll
    for (int r = 0; r < 8; r++)
#pragma unroll
        for (int c = 0; c < 4; c++) acc[r][c] = 0.f;

    for (int kc = 0; kc < D; kc += 32) {
        float4 wreg[4];
#pragma unroll
        for (int i = 0; i < 4; i++)
            wreg[i] = ((const float4*)(W + kc * D))[tid + 256 * i];
        float4 v0 = make_float4(0.f, 0.f, 0.f, 0.f), v1 = v0;
        if (gr < n) {
            v0 = *(const float4*)&x[(size_t)gr * D + kc + sk];
            v1 = *(const float4*)&x[(size_t)gr * D + kc + sk + 16];
        }
        __syncthreads();
#pragma unroll
        for (int i = 0; i < 4; i++)
            ((float4*)Ws)[tid + 256 * i] = wreg[i];
        xT[(sk + 0) * 64 + sr] = v0.x;
        xT[(sk + 1) * 64 + sr] = v0.y;
        xT[(sk + 2) * 64 + sr] = v0.z;
        xT[(sk + 3) * 64 + sr] = v0.w;
        xT[(sk + 16) * 64 + sr] = v1.x;
        xT[(sk + 17) * 64 + sr] = v1.y;
        xT[(sk + 18) * 64 + sr] = v1.z;
        xT[(sk + 19) * 64 + sr] = v1.w;
        __syncthreads();
#pragma unroll 8
        for (int k = 0; k < 32; k++) {
            float4 w  = *(const float4*)&Ws[k * D + tx * 4];
            float4 xa = *(const float4*)&xT[k * 64 + ty * 8];
            float4 xb = *(const float4*)&xT[k * 64 + ty * 8 + 4];
            acc[0][0] = fmaf(xa.x, w.x, acc[0][0]); acc[0][1] = fmaf(xa.x, w.y, acc[0][1]);
            acc[0][2] = fmaf(xa.x, w.z, acc[0][2]); acc[0][3] = fmaf(xa.x, w.w, acc[0][3]);
            acc[1][0] = fmaf(xa.y, w.x, acc[1][0]); acc[1][1] = fmaf(xa.y, w.y, acc[1][1]);
            acc[1][2] = fmaf(xa.y, w.z, acc[1][2]); acc[1][3] = fmaf(xa.y, w.w, acc[1][3]);
            acc[2][0] = fmaf(xa.z, w.x, acc[2][0]); acc[2][1] = fmaf(xa.z, w.y, acc[2][1]);
            acc[2][2] = fmaf(xa.z, w.z, acc[2][2]); acc[2][3] = fmaf(xa.z, w.w, acc[2][3]);
            acc[3][0] = fmaf(xa.w, w.x, acc[3][0]); acc[3][1] = fmaf(xa.w, w.y, acc[3][1]);
            acc[3][2] = fmaf(xa.w, w.z, acc[3][2]); acc[3][3] = fmaf(xa.w, w.w, acc[3][3]);
            acc[4][0] = fmaf(xb.x, w.x, acc[4][0]); acc[4][1] = fmaf(xb.x, w.y, acc[4][1]);
            acc[4][2] = fmaf(xb.x, w.z, acc[4][2]); acc[4][3] = fmaf(xb.x, w.w, acc[4][3]);
            acc[5][0] = fmaf(xb.y, w.x, acc[5][0]); acc[5][1] = fmaf(xb.y, w.y, acc[5][1]);
            acc[5][2] = fmaf(xb.y, w.z, acc[5][2]); acc[5][3] = fmaf(xb.y, w.w, acc[5][3]);
            acc[6][0] = fmaf(xb.z, w.x, acc[6][0]); acc[6][1] = fmaf(xb.z, w.y, acc[6][1]);
            acc[6][2] = fmaf(xb.z, w.z, acc[6][2]); acc[6][3] = fmaf(xb.z, w.w, acc[6][3]);
            acc[7][0] = fmaf(xb.w, w.x, acc[7][0]); acc[7][1] = fmaf(xb.w, w.y, acc[7][1]);
            acc[7][2] = fmaf(xb.w, w.z, acc[7][2]); acc[7][3] = fmaf(xb.w, w.w, acc[7][3]);
        }
    }
#pragma unroll
    for (int r = 0; r < 8; r++) {
        int grr = row0 + ty * 8 + r;
        if (grr < n) {
            float dr = dinv[grr];
            uint2 p;
            p.x = pack_bf16(acc[r][0] * dr, acc[r][1] * dr);
            p.y = pack_bf16(acc[r][2] * dr, acc[r][3] * dr);
            *(uint2*)&hb[(size_t)grr * (D / 2) + tx * 2] = p;
        }
    }
}

// ---------- FUSED layer boundary: aggregate(prev layer) -> LDS tile -> gemm(next W) ----------
// Legal because agg output row d feeds only gemm row d. 512 threads, 64-node tile.
// Phase A: 8 waves x 8 nodes; gather bf16 rows (pre-scaled by dinv[src]), apply
//   dinv[d]*sum + bias, relu, write fp32 straight into xT[k][68] (no global round-trip).
// Phase B: 64x128 gemm from xT; epilogue pre-scales by dinv[row], packs bf16.
// LDS 50 KB -> 3 blocks/CU = 24 waves/CU: phase-A (mem-latency) and phase-B (VALU)
// blocks co-schedule on a CU -> cost ~ max, not sum.

#define XPAD 68   // 64 + 4: keeps b128 reads aligned; phase-A write conflicts bounded

static __global__ __launch_bounds__(512) void aggemm_k(
        const unsigned int* __restrict__ hbin,   // prev h, pre-scaled, packed bf16
        const float* __restrict__ dinv,
        const int* __restrict__ rowptr, const int* __restrict__ csr,
        const float* __restrict__ bias,          // bias of PREV conv (applied in agg)
        const float* __restrict__ W,             // weight of NEXT gemm
        unsigned int* __restrict__ hbout, int n) {
    __shared__ float xT[D * XPAD];   // [k][col] 34.8 KB
    __shared__ float Ws[32 * D];     // 16 KB
    const int tid = threadIdx.x;
    const int row0 = blockIdx.x * 64;

    // ---- phase A ----
    const int wv = tid >> 6;        // wave 0..7
    const int lane = tid & 63;      // feat-pair
    for (int i = 0; i < 8; i++) {
        int lc = wv * 8 + i;
        int nd = row0 + lc;
        if (nd < n) {
            int e = rowptr[nd], end = rowptr[nd + 1];
            float a0 = 0.f, a1 = 0.f;
            for (; e + 7 < end; e += 8) {       // 8 outstanding gathers
                int s0 = csr[e], s1 = csr[e+1], s2 = csr[e+2], s3 = csr[e+3];
                int s4 = csr[e+4], s5 = csr[e+5], s6 = csr[e+6], s7 = csr[e+7];
                unsigned int v0 = hbin[(size_t)s0 * 64 + lane];
                unsigned int v1 = hbin[(size_t)s1 * 64 + lane];
                unsigned int v2 = hbin[(size_t)s2 * 64 + lane];
                unsigned int v3 = hbin[(size_t)s3 * 64 + lane];
                unsigned int v4 = hbin[(size_t)s4 * 64 + lane];
                unsigned int v5 = hbin[(size_t)s5 * 64 + lane];
                unsigned int v6 = hbin[(size_t)s6 * 64 + lane];
                unsigned int v7 = hbin[(size_t)s7 * 64 + lane];
                a0 += bf16_lo(v0); a1 += bf16_hi(v0);
                a0 += bf16_lo(v1); a1 += bf16_hi(v1);
                a0 += bf16_lo(v2); a1 += bf16_hi(v2);
                a0 += bf16_lo(v3); a1 += bf16_hi(v3);
                a0 += bf16_lo(v4); a1 += bf16_hi(v4);
                a0 += bf16_lo(v5); a1 += bf16_hi(v5);
                a0 += bf16_lo(v6); a1 += bf16_hi(v6);
                a0 += bf16_lo(v7); a1 += bf16_hi(v7);
            }
            for (; e < end; e++) {
                int s0 = csr[e];
                unsigned int v0 = hbin[(size_t)s0 * 64 + lane];
                a0 += bf16_lo(v0); a1 += bf16_hi(v0);
            }
            unsigned int hv = hbin[(size_t)nd * 64 + lane];   // self loop (pre-scaled)
            a0 += bf16_lo(hv); a1 += bf16_hi(hv);
            float di = dinv[nd];
            float2 bb = *(const float2*)&bias[lane * 2];
            xT[(2 * lane + 0) * XPAD + lc] = fmaxf(fmaf(di, a0, bb.x), 0.f);
            xT[(2 * lane + 1) * XPAD + lc] = fmaxf(fmaf(di, a1, bb.y), 0.f);
        }
    }
    __syncthreads();

    // ---- phase B: thread = 4 rows x 4 cols ----
    const int tx = tid & 31;        // cols 4*tx..
    const int ty = tid >> 5;        // 0..15 -> rows 4*ty..
    float acc[4][4];
#pragma unroll
    for (int r = 0; r < 4; r++)
#pragma unroll
        for (int c = 0; c < 4; c++) acc[r][c] = 0.f;

    for (int kc = 0; kc < D; kc += 32) {
        float4 w0 = ((const float4*)(W + kc * D))[tid];
        float4 w1 = ((const float4*)(W + kc * D))[tid + 512];
        __syncthreads();            // previous chunk's compute done
        ((float4*)Ws)[tid] = w0;
        ((float4*)Ws)[tid + 512] = w1;
        __syncthreads();
#pragma unroll 8
        for (int k = 0; k < 32; k++) {
            float4 w  = *(const float4*)&Ws[k * D + tx * 4];
            float4 xa = *(const float4*)&xT[(kc + k) * XPAD + ty * 4];
            acc[0][0] = fmaf(xa.x, w.x, acc[0][0]); acc[0][1] = fmaf(xa.x, w.y, acc[0][1]);
            acc[0][2] = fmaf(xa.x, w.z, acc[0][2]); acc[0][3] = fmaf(xa.x, w.w, acc[0][3]);
            acc[1][0] = fmaf(xa.y, w.x, acc[1][0]); acc[1][1] = fmaf(xa.y, w.y, acc[1][1]);
            acc[1][2] = fmaf(xa.y, w.z, acc[1][2]); acc[1][3] = fmaf(xa.y, w.w, acc[1][3]);
            acc[2][0] = fmaf(xa.z, w.x, acc[2][0]); acc[2][1] = fmaf(xa.z, w.y, acc[2][1]);
            acc[2][2] = fmaf(xa.z, w.z, acc[2][2]); acc[2][3] = fmaf(xa.z, w.w, acc[2][3]);
            acc[3][0] = fmaf(xa.w, w.x, acc[3][0]); acc[3][1] = fmaf(xa.w, w.y, acc[3][1]);
            acc[3][2] = fmaf(xa.w, w.z, acc[3][2]); acc[3][3] = fmaf(xa.w, w.w, acc[3][3]);
        }
    }
#pragma unroll
    for (int r = 0; r < 4; r++) {
        int grr = row0 + ty * 4 + r;
        if (grr < n) {
            float dr = dinv[grr];
            uint2 p;
            p.x = pack_bf16(acc[r][0] * dr, acc[r][1] * dr);
            p.y = pack_bf16(acc[r][2] * dr, acc[r][3] * dr);
            *(uint2*)&hbout[(size_t)grr * (D / 2) + tx * 2] = p;
        }
    }
}

// ---------- Final aggregation (layer 3) -> packed bf16 node features ----------

static __global__ __launch_bounds__(256) void agg_k(const unsigned int* __restrict__ hb,
                                                    const float* __restrict__ dinv,
                                                    const int* __restrict__ rowptr,
                                                    const int* __restrict__ csr,
                                                    const float* __restrict__ b,
                                                    unsigned int* __restrict__ outp, int n) {
    int node = blockIdx.x * 4 + (threadIdx.x >> 6);
    if (node >= n) return;
    const int lane = threadIdx.x & 63;
    int e = rowptr[node], end = rowptr[node + 1];
    float a0 = 0.f, a1 = 0.f;
    for (; e + 3 < end; e += 4) {
        int s0 = csr[e], s1 = csr[e + 1], s2 = csr[e + 2], s3 = csr[e + 3];
        unsigned int v0 = hb[(size_t)s0 * 64 + lane];
        unsigned int v1 = hb[(size_t)s1 * 64 + lane];
        unsigned int v2 = hb[(size_t)s2 * 64 + lane];
        unsigned int v3 = hb[(size_t)s3 * 64 + lane];
        a0 += bf16_lo(v0); a1 += bf16_hi(v0);
        a0 += bf16_lo(v1); a1 += bf16_hi(v1);
        a0 += bf16_lo(v2); a1 += bf16_hi(v2);
        a0 += bf16_lo(v3); a1 += bf16_hi(v3);
    }
    for (; e < end; e++) {
        int s0 = csr[e];
        unsigned int v0 = hb[(size_t)s0 * 64 + lane];
        a0 += bf16_lo(v0); a1 += bf16_hi(v0);
    }
    unsigned int hv = hb[(size_t)node * 64 + lane];
    a0 += bf16_lo(hv); a1 += bf16_hi(hv);
    float di = dinv[node];
    float2 bb = *(const float2*)&b[lane * 2];
    float o0 = fmaxf(fmaf(di, a0, bb.x), 0.f);
    float o1 = fmaxf(fmaf(di, a1, bb.y), 0.f);
    outp[(size_t)node * 64 + lane] = pack_bf16(o0, o1);
}

// ---------- Fused mean-pool + classifier ----------

static __global__ __launch_bounds__(256) void poolcls_k(const unsigned int* __restrict__ xp,
                                                        const int* __restrict__ batch, int n,
                                                        const float* __restrict__ Wc,
                                                        const float* __restrict__ bc,
                                                        const float* __restrict__ Wo,
                                                        const float* __restrict__ bo,
                                                        float* __restrict__ out) {
    int g = blockIdx.x;
    int f = threadIdx.x & 127;
    int half = threadIdx.x >> 7;
    int lo = 0, hi = n;
    while (lo < hi) { int m = (lo + hi) >> 1; if (batch[m] < g) lo = m + 1; else hi = m; }
    int start = lo;
    hi = n;
    while (lo < hi) { int m = (lo + hi) >> 1; if (batch[m] < g + 1) lo = m + 1; else hi = m; }
    int end = lo;
    float s = 0.f;
    const int ui = f >> 1;
    const bool hif = f & 1;
    for (int r = start + half; r < end; r += 2) {
        unsigned int u = xp[(size_t)r * 64 + ui];
        s += hif ? bf16_hi(u) : bf16_lo(u);
    }
    __shared__ float red[256];
    __shared__ float pooled[D];
    red[threadIdx.x] = s;
    __syncthreads();
    if (half == 0) {
        float tot = red[f] + red[f + 128];
        float c = (float)(end - start);
        pooled[f] = tot / fmaxf(c, 1.0f);
    }
    __syncthreads();
    int t = threadIdx.x;
    if (t < H) {
        float z = bc[t];
        for (int k = 0; k < D; k++) z = fmaf(pooled[k], Wc[k * H + t], z);
        z = fmaxf(z, 0.f);
        float v = z * Wo[t];
        for (int off = 32; off > 0; off >>= 1) v += __shfl_down(v, off);
        if (t == 0) out[g] = v + bo[0];
    }
}

// ---------- Orchestration ----------

extern "C" void kernel_launch(void* const* d_in, const int* in_sizes, int n_in,
                              void* d_out, int out_size, void* d_ws, size_t ws_size,
                              hipStream_t stream) {
    const float* x     = (const float*)d_in[0];
    const int*   ei    = (const int*)d_in[1];
    const int*   batch = (const int*)d_in[2];
    const float* W1 = (const float*)d_in[3];
    const float* b1 = (const float*)d_in[4];
    const float* W2 = (const float*)d_in[5];
    const float* b2 = (const float*)d_in[6];
    const float* W3 = (const float*)d_in[7];
    const float* b3 = (const float*)d_in[8];
    const float* Wc = (const float*)d_in[9];
    const float* bc = (const float*)d_in[10];
    const float* Wo = (const float*)d_in[11];
    const float* bo = (const float*)d_in[12];

    const int n = in_sizes[0] / D;
    const int E = in_sizes[1] / 2;
    const int G = out_size;

    char* ws = (char*)d_ws;
    size_t off = 0;
    auto alloc = [&](size_t bytes) -> void* {
        void* p = ws + off;
        off = (off + bytes + 255) & ~(size_t)255;
        return p;
    };
    int*   cnt     = (int*)alloc((size_t)n * 4);
    int*   rowptr  = (int*)alloc((size_t)(n + 1) * 4);
    int*   bsum    = (int*)alloc(1024);
    float* dinv    = (float*)alloc((size_t)n * 4);
    int*   rank    = (int*)alloc((size_t)E * 4);
    int*   csr_src = (int*)alloc((size_t)E * 4);
    unsigned int* hbA  = (unsigned int*)alloc((size_t)n * (D / 2) * 4);  // packed bf16, pre-scaled
    unsigned int* hbB  = (unsigned int*)alloc((size_t)n * (D / 2) * 4);
    unsigned int* xbuf = (unsigned int*)alloc((size_t)n * (D / 2) * 4);  // final node feats
    (void)ws_size; (void)n_in;

    hipMemsetAsync(cnt, 0, (size_t)n * 4, stream);

    const int TB = 256;
    const int nb = (n + 255) / 256;
    const int gemm_blocks = (n + 63) / 64;
    const int p2_blocks   = (E + TB - 1) / TB;
    const int agg_blocks  = (n + 3) / 4;

    pass1_k<<<(E + TB - 1) / TB, TB, 0, stream>>>(ei, E, cnt, rank);
    scanA_k<<<nb, 256, 0, stream>>>(cnt, n, bsum, dinv);
    scanB_k<<<1, 256, 0, stream>>>(bsum, nb);
    scanC_k<<<nb, 256, 0, stream>>>(cnt, n, bsum, rowptr);

    // gemm layer-1 (indep of CSR) overlapped with pass2 scatter
    gemm1_pass2_k<<<gemm_blocks + p2_blocks, 256, 0, stream>>>(
        x, W1, dinv, hbA, n, gemm_blocks, ei, E, rank, rowptr, csr_src);

    // fused boundaries: agg(prev) -> gemm(next)
    aggemm_k<<<gemm_blocks, 512, 0, stream>>>(hbA, dinv, rowptr, csr_src, b1, W2, hbB, n);
    aggemm_k<<<gemm_blocks, 512, 0, stream>>>(hbB, dinv, rowptr, csr_src, b2, W3, hbA, n);

    // final aggregation + pooled classifier
    agg_k<<<agg_blocks, 256, 0, stream>>>(hbA, dinv, rowptr, csr_src, b3, xbuf, n);
    poolcls_k<<<G, 256, 0, stream>>>(xbuf, batch, n, Wc, bc, Wo, bo, (float*)d_out);
}

// Round 7
// 360.383 us; speedup vs baseline: 1.1647x; 1.1647x over previous
//
#include <hip/hip_runtime.h>

#define D 128   // feature dim
#define H 64    // hidden dim of classifier

// ---------- bf16 helpers (bit-level, RNE) ----------

__device__ __forceinline__ unsigned int bf16_rne(float f) {
    unsigned int u = __float_as_uint(f);
    u += 0x7fffu + ((u >> 16) & 1u);
    return u >> 16;
}
__device__ __forceinline__ unsigned int pack_bf16(float a, float b) {
    return bf16_rne(a) | (bf16_rne(b) << 16);
}
__device__ __forceinline__ float bf16_lo(unsigned int u) { return __uint_as_float(u << 16); }
__device__ __forceinline__ float bf16_hi(unsigned int u) { return __uint_as_float(u & 0xffff0000u); }

// ---------- FAT: gemm layer-1 (fp32 x @ W1 -> UNSCALED bf16) ∥ CSR pass1 (atomic rank) ----------
// gemm1 needs no dinv (layer-1 agg applies dinv[s] per edge via scalar load), so it can
// run concurrently with the degree-count pass. gemm = VALU-bound, pass1 = atomic-latency.

static __global__ __launch_bounds__(256) void fat1_k(
        const float* __restrict__ x, const float* __restrict__ W,
        unsigned int* __restrict__ hb, int n, int gb,
        const int* __restrict__ ei, int E,
        int* __restrict__ cnt, int* __restrict__ rank) {
    __shared__ float Ws[32 * D];     // [kk][col] 16 KB
    __shared__ float xT[32 * 64];    // [kk][row]  8 KB
    const int tid = threadIdx.x;
    if ((int)blockIdx.x >= gb) {     // ---- pass1 ----
        int e = ((int)blockIdx.x - gb) * 256 + tid;
        if (e < E) rank[e] = atomicAdd(&cnt[ei[E + e]], 1);
        return;
    }
    // ---- gemm1 (r5 structure, unscaled epilogue) ----
    const int row0 = blockIdx.x * 64;
    const int tx = tid & 31;
    const int ty = tid >> 5;
    const int sr = tid & 63;
    const int sk = (tid >> 6) * 4;
    const int gr = row0 + sr;

    float acc[8][4];
#pragma unroll
    for (int r = 0; r < 8; r++)
#pragma unroll
        for (int c = 0; c < 4; c++) acc[r][c] = 0.f;

    for (int kc = 0; kc < D; kc += 32) {
        float4 wreg[4];
#pragma unroll
        for (int i = 0; i < 4; i++)
            wreg[i] = ((const float4*)(W + kc * D))[tid + 256 * i];
        float4 v0 = make_float4(0.f, 0.f, 0.f, 0.f), v1 = v0;
        if (gr < n) {
            v0 = *(const float4*)&x[(size_t)gr * D + kc + sk];
            v1 = *(const float4*)&x[(size_t)gr * D + kc + sk + 16];
        }
        __syncthreads();
#pragma unroll
        for (int i = 0; i < 4; i++)
            ((float4*)Ws)[tid + 256 * i] = wreg[i];
        xT[(sk + 0) * 64 + sr] = v0.x;
        xT[(sk + 1) * 64 + sr] = v0.y;
        xT[(sk + 2) * 64 + sr] = v0.z;
        xT[(sk + 3) * 64 + sr] = v0.w;
        xT[(sk + 16) * 64 + sr] = v1.x;
        xT[(sk + 17) * 64 + sr] = v1.y;
        xT[(sk + 18) * 64 + sr] = v1.z;
        xT[(sk + 19) * 64 + sr] = v1.w;
        __syncthreads();
#pragma unroll 8
        for (int k = 0; k < 32; k++) {
            float4 w  = *(const float4*)&Ws[k * D + tx * 4];
            float4 xa = *(const float4*)&xT[k * 64 + ty * 8];
            float4 xb = *(const float4*)&xT[k * 64 + ty * 8 + 4];
            acc[0][0] = fmaf(xa.x, w.x, acc[0][0]); acc[0][1] = fmaf(xa.x, w.y, acc[0][1]);
            acc[0][2] = fmaf(xa.x, w.z, acc[0][2]); acc[0][3] = fmaf(xa.x, w.w, acc[0][3]);
            acc[1][0] = fmaf(xa.y, w.x, acc[1][0]); acc[1][1] = fmaf(xa.y, w.y, acc[1][1]);
            acc[1][2] = fmaf(xa.y, w.z, acc[1][2]); acc[1][3] = fmaf(xa.y, w.w, acc[1][3]);
            acc[2][0] = fmaf(xa.z, w.x, acc[2][0]); acc[2][1] = fmaf(xa.z, w.y, acc[2][1]);
            acc[2][2] = fmaf(xa.z, w.z, acc[2][2]); acc[2][3] = fmaf(xa.z, w.w, acc[2][3]);
            acc[3][0] = fmaf(xa.w, w.x, acc[3][0]); acc[3][1] = fmaf(xa.w, w.y, acc[3][1]);
            acc[3][2] = fmaf(xa.w, w.z, acc[3][2]); acc[3][3] = fmaf(xa.w, w.w, acc[3][3]);
            acc[4][0] = fmaf(xb.x, w.x, acc[4][0]); acc[4][1] = fmaf(xb.x, w.y, acc[4][1]);
            acc[4][2] = fmaf(xb.x, w.z, acc[4][2]); acc[4][3] = fmaf(xb.x, w.w, acc[4][3]);
            acc[5][0] = fmaf(xb.y, w.x, acc[5][0]); acc[5][1] = fmaf(xb.y, w.y, acc[5][1]);
            acc[5][2] = fmaf(xb.y, w.z, acc[5][2]); acc[5][3] = fmaf(xb.y, w.w, acc[5][3]);
            acc[6][0] = fmaf(xb.z, w.x, acc[6][0]); acc[6][1] = fmaf(xb.z, w.y, acc[6][1]);
            acc[6][2] = fmaf(xb.z, w.z, acc[6][2]); acc[6][3] = fmaf(xb.z, w.w, acc[6][3]);
            acc[7][0] = fmaf(xb.w, w.x, acc[7][0]); acc[7][1] = fmaf(xb.w, w.y, acc[7][1]);
            acc[7][2] = fmaf(xb.w, w.z, acc[7][2]); acc[7][3] = fmaf(xb.w, w.w, acc[7][3]);
        }
    }
#pragma unroll
    for (int r = 0; r < 8; r++) {
        int grr = row0 + ty * 8 + r;
        if (grr < n) {
            uint2 p;
            p.x = pack_bf16(acc[r][0], acc[r][1]);
            p.y = pack_bf16(acc[r][2], acc[r][3]);
            *(uint2*)&hb[(size_t)grr * (D / 2) + tx * 2] = p;
        }
    }
}

// ---------- scans (scanA fuses dinv) ----------

static __global__ void scanA_k(const int* __restrict__ cnt, int n,
                               int* __restrict__ bsum, float* __restrict__ dinv) {
    __shared__ int s[256];
    int i = blockIdx.x * 256 + threadIdx.x;
    int v = (i < n) ? cnt[i] : 0;
    if (i < n) dinv[i] = rsqrtf((float)v + 1.0f);   // +1 self loop; deg >= 1 always
    s[threadIdx.x] = v;
    __syncthreads();
    for (int off = 128; off > 0; off >>= 1) {
        if ((int)threadIdx.x < off) s[threadIdx.x] += s[threadIdx.x + off];
        __syncthreads();
    }
    if (threadIdx.x == 0) bsum[blockIdx.x] = s[0];
}

static __global__ __launch_bounds__(256) void scanB_k(int* __restrict__ bsum, int nb) {
    __shared__ int s[256];
    __shared__ int carry;
    if (threadIdx.x == 0) carry = 0;
    __syncthreads();
    for (int base = 0; base < nb; base += 256) {
        int i = base + threadIdx.x;
        int v = (i < nb) ? bsum[i] : 0;
        s[threadIdx.x] = v;
        __syncthreads();
        for (int off = 1; off < 256; off <<= 1) {
            int t = ((int)threadIdx.x >= off) ? s[threadIdx.x - off] : 0;
            __syncthreads();
            s[threadIdx.x] += t;
            __syncthreads();
        }
        if (i < nb) bsum[i] = carry + s[threadIdx.x] - v;   // exclusive
        __syncthreads();
        if (threadIdx.x == 255) carry += s[255];
        __syncthreads();
    }
}

static __global__ void scanC_k(const int* __restrict__ cnt, int n, const int* __restrict__ bsum,
                               int* __restrict__ rowptr) {
    __shared__ int s[256];
    int i = blockIdx.x * 256 + threadIdx.x;
    int v = (i < n) ? cnt[i] : 0;
    s[threadIdx.x] = v;
    __syncthreads();
    for (int off = 1; off < 256; off <<= 1) {
        int t = ((int)threadIdx.x >= off) ? s[threadIdx.x - off] : 0;
        __syncthreads();
        s[threadIdx.x] += t;
        __syncthreads();
    }
    if (i < n) {
        int excl = bsum[blockIdx.x] + s[threadIdx.x] - v;
        rowptr[i] = excl;
        if (i == n - 1) rowptr[n] = excl + v;
    }
}

static __global__ void pass2_k(const int* __restrict__ ei, int E,
                               const int* __restrict__ rank,
                               const int* __restrict__ rowptr,
                               int* __restrict__ csr_src) {
    int e = blockIdx.x * blockDim.x + threadIdx.x;
    if (e < E) {
        int d = ei[E + e];
        csr_src[rowptr[d] + rank[e]] = ei[e];   // no atomics
    }
}

// ---------- Aggregation + bias + relu ----------
// 1 wave per node; node forced into SGPR (readfirstlane) so rowptr/csr/dinv loads are
// scalar s_loads riding under the 256 B vector gathers. Edge loop = ceil(deg/8) batches
// of 8 clamped+predicated gathers: no serial remainder tail, 8 outstanding loads/wave.
// SCALED: hb rows pre-scaled by dinv[src] (layers 2,3). Else dinv[s] applied per edge.

template <bool SCALED>
static __global__ __launch_bounds__(256) void agg_k(const unsigned int* __restrict__ hb,
                                                    const float* __restrict__ dinv,
                                                    const int* __restrict__ rowptr,
                                                    const int* __restrict__ csr,
                                                    const float* __restrict__ b,
                                                    unsigned int* __restrict__ outp, int n) {
    int node = blockIdx.x * 4 + (threadIdx.x >> 6);
    node = __builtin_amdgcn_readfirstlane(node);
    if (node >= n) return;
    const int lane = threadIdx.x & 63;
    const int beg = rowptr[node], end = rowptr[node + 1];
    float a0 = 0.f, a1 = 0.f;
    for (int base = beg; base < end; base += 8) {
        int s[8];
        float w[8];
#pragma unroll
        for (int i = 0; i < 8; i++) {
            int ee = base + i;
            int ec = (ee < end) ? ee : end - 1;     // clamp (scalar min)
            s[i] = csr[ec];
        }
#pragma unroll
        for (int i = 0; i < 8; i++) {
            bool live = (base + i) < end;
            if constexpr (SCALED) w[i] = live ? 1.0f : 0.0f;
            else                  w[i] = live ? dinv[s[i]] : 0.0f;
        }
#pragma unroll
        for (int i = 0; i < 8; i++) {
            unsigned int v = hb[(size_t)s[i] * 64 + lane];
            a0 = fmaf(w[i], bf16_lo(v), a0);
            a1 = fmaf(w[i], bf16_hi(v), a1);
        }
    }
    float di = dinv[node];
    unsigned int hv = hb[(size_t)node * 64 + lane];   // self loop
    if constexpr (SCALED) { a0 += bf16_lo(hv);            a1 += bf16_hi(hv); }
    else                  { a0 = fmaf(di, bf16_lo(hv), a0); a1 = fmaf(di, bf16_hi(hv), a1); }
    float2 bb = *(const float2*)&b[lane * 2];
    float o0 = fmaxf(fmaf(di, a0, bb.x), 0.f);
    float o1 = fmaxf(fmaf(di, a1, bb.y), 0.f);
    outp[(size_t)node * 64 + lane] = pack_bf16(o0, o1);
}

// ---------- GEMM layers 2/3: hb = bf16( dinv[row] * (xpacked @ W) ) ----------

static __global__ __launch_bounds__(256) void gemm_k(const unsigned int* __restrict__ xp,
                                                     const float* __restrict__ W,
                                                     const float* __restrict__ dinv,
                                                     unsigned int* __restrict__ hb, int n) {
    __shared__ float Ws[32 * D];     // 16 KB
    __shared__ float xT[32 * 64];    //  8 KB
    const int tid = threadIdx.x;
    const int row0 = blockIdx.x * 64;
    const int tx = tid & 31;
    const int ty = tid >> 5;
    const int sr = tid & 63;
    const int sk = (tid >> 6) * 4;
    const int gr = row0 + sr;

    float acc[8][4];
#pragma unroll
    for (int r = 0; r < 8; r++)
#pragma unroll
        for (int c = 0; c < 4; c++) acc[r][c] = 0.f;

    for (int kc = 0; kc < D; kc += 32) {
        float4 wreg[4];
#pragma unroll
        for (int i = 0; i < 4; i++)
            wreg[i] = ((const float4*)(W + kc * D))[tid + 256 * i];
        float4 v0 = make_float4(0.f, 0.f, 0.f, 0.f), v1 = v0;
        if (gr < n) {
            const uint2* x2 = (const uint2*)xp;
            uint2 u0 = x2[(size_t)gr * 32 + ((kc + sk) >> 2)];
            uint2 u1 = x2[(size_t)gr * 32 + ((kc + sk + 16) >> 2)];
            v0 = make_float4(bf16_lo(u0.x), bf16_hi(u0.x), bf16_lo(u0.y), bf16_hi(u0.y));
            v1 = make_float4(bf16_lo(u1.x), bf16_hi(u1.x), bf16_lo(u1.y), bf16_hi(u1.y));
        }
        __syncthreads();
#pragma unroll
        for (int i = 0; i < 4; i++)
            ((float4*)Ws)[tid + 256 * i] = wreg[i];
        xT[(sk + 0) * 64 + sr] = v0.x;
        xT[(sk + 1) * 64 + sr] = v0.y;
        xT[(sk + 2) * 64 + sr] = v0.z;
        xT[(sk + 3) * 64 + sr] = v0.w;
        xT[(sk + 16) * 64 + sr] = v1.x;
        xT[(sk + 17) * 64 + sr] = v1.y;
        xT[(sk + 18) * 64 + sr] = v1.z;
        xT[(sk + 19) * 64 + sr] = v1.w;
        __syncthreads();
#pragma unroll 8
        for (int k = 0; k < 32; k++) {
            float4 w  = *(const float4*)&Ws[k * D + tx * 4];
            float4 xa = *(const float4*)&xT[k * 64 + ty * 8];
            float4 xb = *(const float4*)&xT[k * 64 + ty * 8 + 4];
            acc[0][0] = fmaf(xa.x, w.x, acc[0][0]); acc[0][1] = fmaf(xa.x, w.y, acc[0][1]);
            acc[0][2] = fmaf(xa.x, w.z, acc[0][2]); acc[0][3] = fmaf(xa.x, w.w, acc[0][3]);
            acc[1][0] = fmaf(xa.y, w.x, acc[1][0]); acc[1][1] = fmaf(xa.y, w.y, acc[1][1]);
            acc[1][2] = fmaf(xa.y, w.z, acc[1][2]); acc[1][3] = fmaf(xa.y, w.w, acc[1][3]);
            acc[2][0] = fmaf(xa.z, w.x, acc[2][0]); acc[2][1] = fmaf(xa.z, w.y, acc[2][1]);
            acc[2][2] = fmaf(xa.z, w.z, acc[2][2]); acc[2][3] = fmaf(xa.z, w.w, acc[2][3]);
            acc[3][0] = fmaf(xa.w, w.x, acc[3][0]); acc[3][1] = fmaf(xa.w, w.y, acc[3][1]);
            acc[3][2] = fmaf(xa.w, w.z, acc[3][2]); acc[3][3] = fmaf(xa.w, w.w, acc[3][3]);
            acc[4][0] = fmaf(xb.x, w.x, acc[4][0]); acc[4][1] = fmaf(xb.x, w.y, acc[4][1]);
            acc[4][2] = fmaf(xb.x, w.z, acc[4][2]); acc[4][3] = fmaf(xb.x, w.w, acc[4][3]);
            acc[5][0] = fmaf(xb.y, w.x, acc[5][0]); acc[5][1] = fmaf(xb.y, w.y, acc[5][1]);
            acc[5][2] = fmaf(xb.y, w.z, acc[5][2]); acc[5][3] = fmaf(xb.y, w.w, acc[5][3]);
            acc[6][0] = fmaf(xb.z, w.x, acc[6][0]); acc[6][1] = fmaf(xb.z, w.y, acc[6][1]);
            acc[6][2] = fmaf(xb.z, w.z, acc[6][2]); acc[6][3] = fmaf(xb.z, w.w, acc[6][3]);
            acc[7][0] = fmaf(xb.w, w.x, acc[7][0]); acc[7][1] = fmaf(xb.w, w.y, acc[7][1]);
            acc[7][2] = fmaf(xb.w, w.z, acc[7][2]); acc[7][3] = fmaf(xb.w, w.w, acc[7][3]);
        }
    }
#pragma unroll
    for (int r = 0; r < 8; r++) {
        int grr = row0 + ty * 8 + r;
        if (grr < n) {
            float dr = dinv[grr];
            uint2 p;
            p.x = pack_bf16(acc[r][0] * dr, acc[r][1] * dr);
            p.y = pack_bf16(acc[r][2] * dr, acc[r][3] * dr);
            *(uint2*)&hb[(size_t)grr * (D / 2) + tx * 2] = p;
        }
    }
}

// ---------- Fused mean-pool + classifier ----------

static __global__ __launch_bounds__(256) void poolcls_k(const unsigned int* __restrict__ xp,
                                                        const int* __restrict__ batch, int n,
                                                        const float* __restrict__ Wc,
                                                        const float* __restrict__ bc,
                                                        const float* __restrict__ Wo,
                                                        const float* __restrict__ bo,
                                                        float* __restrict__ out) {
    int g = blockIdx.x;
    int f = threadIdx.x & 127;
    int half = threadIdx.x >> 7;
    int lo = 0, hi = n;
    while (lo < hi) { int m = (lo + hi) >> 1; if (batch[m] < g) lo = m + 1; else hi = m; }
    int start = lo;
    hi = n;
    while (lo < hi) { int m = (lo + hi) >> 1; if (batch[m] < g + 1) lo = m + 1; else hi = m; }
    int end = lo;
    float s = 0.f;
    const int ui = f >> 1;
    const bool hif = f & 1;
    for (int r = start + half; r < end; r += 2) {
        unsigned int u = xp[(size_t)r * 64 + ui];
        s += hif ? bf16_hi(u) : bf16_lo(u);
    }
    __shared__ float red[256];
    __shared__ float pooled[D];
    red[threadIdx.x] = s;
    __syncthreads();
    if (half == 0) {
        float tot = red[f] + red[f + 128];
        float c = (float)(end - start);
        pooled[f] = tot / fmaxf(c, 1.0f);
    }
    __syncthreads();
    int t = threadIdx.x;
    if (t < H) {
        float z = bc[t];
        for (int k = 0; k < D; k++) z = fmaf(pooled[k], Wc[k * H + t], z);
        z = fmaxf(z, 0.f);
        float v = z * Wo[t];
        for (int off = 32; off > 0; off >>= 1) v += __shfl_down(v, off);
        if (t == 0) out[g] = v + bo[0];
    }
}

// ---------- Orchestration ----------

extern "C" void kernel_launch(void* const* d_in, const int* in_sizes, int n_in,
                              void* d_out, int out_size, void* d_ws, size_t ws_size,
                              hipStream_t stream) {
    const float* x     = (const float*)d_in[0];
    const int*   ei    = (const int*)d_in[1];
    const int*   batch = (const int*)d_in[2];
    const float* W1 = (const float*)d_in[3];
    const float* b1 = (const float*)d_in[4];
    const float* W2 = (const float*)d_in[5];
    const float* b2 = (const float*)d_in[6];
    const float* W3 = (const float*)d_in[7];
    const float* b3 = (const float*)d_in[8];
    const float* Wc = (const float*)d_in[9];
    const float* bc = (const float*)d_in[10];
    const float* Wo = (const float*)d_in[11];
    const float* bo = (const float*)d_in[12];

    const int n = in_sizes[0] / D;
    const int E = in_sizes[1] / 2;
    const int G = out_size;

    char* ws = (char*)d_ws;
    size_t off = 0;
    auto alloc = [&](size_t bytes) -> void* {
        void* p = ws + off;
        off = (off + bytes + 255) & ~(size_t)255;
        return p;
    };
    int*   cnt     = (int*)alloc((size_t)n * 4);
    int*   rowptr  = (int*)alloc((size_t)(n + 1) * 4);
    int*   bsum    = (int*)alloc(1024);
    float* dinv    = (float*)alloc((size_t)n * 4);
    int*   rank    = (int*)alloc((size_t)E * 4);
    int*   csr_src = (int*)alloc((size_t)E * 4);
    unsigned int* hb = (unsigned int*)alloc((size_t)n * (D / 2) * 4);  // packed bf16 gemm out
    unsigned int* xb = (unsigned int*)alloc((size_t)n * (D / 2) * 4);  // packed bf16 agg out
    (void)ws_size; (void)n_in;

    hipMemsetAsync(cnt, 0, (size_t)n * 4, stream);

    const int TB = 256;
    const int nb = (n + 255) / 256;
    const int gemm_blocks = (n + 63) / 64;
    const int p1_blocks   = (E + TB - 1) / TB;
    const int agg_blocks  = (n + 3) / 4;

    // gemm1 (unscaled out, indep of CSR) overlapped with pass1 rank/histogram
    fat1_k<<<gemm_blocks + p1_blocks, 256, 0, stream>>>(
        x, W1, hb, n, gemm_blocks, ei, E, cnt, rank);

    scanA_k<<<nb, 256, 0, stream>>>(cnt, n, bsum, dinv);
    scanB_k<<<1, 256, 0, stream>>>(bsum, nb);
    scanC_k<<<nb, 256, 0, stream>>>(cnt, n, bsum, rowptr);
    pass2_k<<<p1_blocks, TB, 0, stream>>>(ei, E, rank, rowptr, csr_src);

    // layer 1: per-edge dinv[s] (hb unscaled)
    agg_k<false><<<agg_blocks, 256, 0, stream>>>(hb, dinv, rowptr, csr_src, b1, xb, n);
    // layers 2,3: pre-scaled hb
    gemm_k<<<gemm_blocks, 256, 0, stream>>>(xb, W2, dinv, hb, n);
    agg_k<true><<<agg_blocks, 256, 0, stream>>>(hb, dinv, rowptr, csr_src, b2, xb, n);
    gemm_k<<<gemm_blocks, 256, 0, stream>>>(xb, W3, dinv, hb, n);
    agg_k<true><<<agg_blocks, 256, 0, stream>>>(hb, dinv, rowptr, csr_src, b3, xb, n);

    poolcls_k<<<G, 256, 0, stream>>>(xb, batch, n, Wc, bc, Wo, bo, (float*)d_out);
}